// Round 2
// baseline (760.711 us; speedup 1.0000x reference)
//
#include <hip/hip_runtime.h>
#include <math.h>

typedef float v4f __attribute__((ext_vector_type(4)));
typedef short v8s __attribute__((ext_vector_type(8)));

#define NBATCH 4096
#define NT 64
#define HD 256
#define UD 128
#define ZD 16
#define AD 64
#define LRSCALE 0.25f

// output offsets (floats) in d_out: c, z_next, attn, q, k, v
#define OFF_C    0UL
#define OFF_ZN   33554432UL
#define OFF_ATTN 37748736UL
#define OFF_Q    54525952UL
#define OFF_K    71303168UL
#define OFF_V    88080384UL

// d_ws layout:
//  shorts (bf16): WT1 [48][288] @0  (n<4: qd_down col n over K=[h|z](272);
//                 n in 16..47: gate/cand weight h,z rows, transposed)
//                 WT2 [16][128] @13824 (n<4: kd_down, n 4..7: vd_down)
//  f32 (at short offset 15872 = byte 31744):
//                 M4   [4][4]   @f+0    = SCALE^2/8 * qd_up @ kd_up^T
//                 C4UP [4][128] @f+16   = SCALE^2 * vd_up @ od_down @ od_up
//                 G4   [4][32]  @f+528  = C4UP @ W[272:400] (gate|cand)
#define WS_WT2OFF 13824
#define WS_SHORTS 15872
#define F_M4   0
#define F_C4UP 16
#define F_G4   528

__device__ __forceinline__ short f2bf(float x) {
  unsigned u = __float_as_uint(x);
  u = (u + 0x7fffu + ((u >> 16) & 1u)) >> 16;  // RNE
  return (short)u;
}
__device__ __forceinline__ v8s ld8(const short* p) { return *(const v8s*)p; }

__device__ __forceinline__ unsigned cvt2(float lo, float hi) {
  unsigned r;
  asm("v_cvt_pk_bf16_f32 %0, %1, %2" : "=v"(r) : "v"(lo), "v"(hi));
  return r;
}
__device__ __forceinline__ v8s pack8(v4f x0, v4f x1) {
  union { unsigned u[4]; v8s s; } z;
  z.u[0] = cvt2(x0.x, x0.y);
  z.u[1] = cvt2(x0.z, x0.w);
  z.u[2] = cvt2(x1.x, x1.y);
  z.u[3] = cvt2(x1.z, x1.w);
  return z.s;
}

// ---------------- setup kernel: pre-transpose bf16 weights + rank-4 fused f32 mats ----------------
__global__ void prep_weights(
    const float* __restrict__ qd_down, const float* __restrict__ qd_up,
    const float* __restrict__ kd_down, const float* __restrict__ kd_up,
    const float* __restrict__ vd_down, const float* __restrict__ vd_up,
    const float* __restrict__ od_down, const float* __restrict__ od_up,
    const float* __restrict__ ug_w, const float* __restrict__ cand_w,
    short* __restrict__ ws)
{
  __shared__ float p44s[16];
  __shared__ float c4up_s[512];
  const int tid = threadIdx.x;

  // bf16 sections, spread over all blocks
  for (int idx = blockIdx.x * 256 + tid; idx < WS_SHORTS; idx += 8 * 256) {
    float val = 0.f;
    if (idx < WS_WT2OFF) {
      int n = idx / 288, k = idx - n * 288;
      if (n < 4) {
        if (k < 272) val = qd_down[k * 4 + n];
      } else if (n >= 16) {
        const float* W = (n < 32) ? ug_w : cand_w;  // mix=[z,h,c]
        int o = (n < 32) ? (n - 16) : (n - 32);
        if (k < 256) val = W[(16 + k) * 16 + o];          // h rows
        else if (k < 272) val = W[(k - 256) * 16 + o];    // z rows
      }
    } else {
      int j = idx - WS_WT2OFF;
      int n = j >> 7, k = j & 127;
      if (n < 4) val = kd_down[k * 4 + n];
      else if (n < 8) val = vd_down[k * 4 + (n - 4)];
    }
    ws[idx] = f2bf(val);
  }

  if (blockIdx.x != 0) return;
  float* wsf = (float*)(ws + WS_SHORTS);

  // M4[r][s] = SCALE^2/8 * sum_d qd_up[r][d]*kd_up[s][d];  P44[j][i] = SCALE^2 * sum_d vd_up[j][d]*od_down[d][i]
  if (tid < 16) {
    int r = tid >> 2, s = tid & 3;
    float acc = 0.f;
    for (int d = 0; d < 64; ++d) acc += qd_up[r * 64 + d] * kd_up[s * 64 + d];
    wsf[F_M4 + tid] = acc * (LRSCALE * LRSCALE * 0.125f);
  } else if (tid < 32) {
    int j = (tid - 16) >> 2, i2 = tid & 3;
    float acc = 0.f;
    for (int d = 0; d < 64; ++d) acc += vd_up[j * 64 + d] * od_down[d * 4 + i2];
    p44s[tid - 16] = acc * (LRSCALE * LRSCALE);
  }
  __syncthreads();
  // C4UP[j][e] = sum_i P44[j][i] * od_up[i][e]
  for (int idx = tid; idx < 512; idx += 256) {
    int j = idx >> 7, e = idx & 127;
    float acc = 0.f;
    for (int i2 = 0; i2 < 4; ++i2) acc += p44s[j * 4 + i2] * od_up[i2 * 128 + e];
    c4up_s[idx] = acc;
    wsf[F_C4UP + idx] = acc;
  }
  __syncthreads();
  // G4[j][o] = sum_e C4UP[j][e] * Wc[272+e][o]
  if (tid < 128) {
    int j = tid >> 5, o = tid & 31;
    const float* W = (o < 16) ? ug_w : cand_w;
    float acc = 0.f;
    for (int e = 0; e < 128; ++e) acc += c4up_s[j * 128 + e] * W[(272 + e) * 16 + (o & 15)];
    wsf[F_G4 + tid] = acc;
  }
}

// ---------------- main kernel: one workgroup per batch, 256 threads = 4 waves, 2 barriers ----------------
// Rank-4 attention: scores = (q4@M4)@k4^T; cl4 = attn@v4 (in-register); c = cl4@C4UP; g1c = cl4@G4.
__global__ __launch_bounds__(256, 4)
void memetic_fused(
    const float* __restrict__ hg, const float* __restrict__ ug2,
    const float* __restrict__ zg,
    const float* __restrict__ qd_up, const float* __restrict__ kd_up,
    const float* __restrict__ vd_up,
    const float* __restrict__ ug_b, const float* __restrict__ cand_b,
    const float* __restrict__ eta_logit,
    const short* __restrict__ wsw,
    float* __restrict__ c_o, float* __restrict__ zn_o,
    float* __restrict__ attn_o, float* __restrict__ q_o,
    float* __restrict__ k_o, float* __restrict__ v_o)
{
  __shared__ float g1out[NT * 33];      // gate_pre[0..15], cand_pre[16..31]
  __shared__ float q4s[NT * 4];         // q4 per token
  __shared__ float kv8[NT * 8 + 16];    // row m at m*8 + (m>>4)*4 : k4[0..3], v4[4..7] (bank-skewed)
  __shared__ float cl4s[NT * 4];        // cl4 = attn @ v4
  __shared__ float c4up_lds[512];       // [4][128]
  __shared__ float g4_lds[128];         // [4][32]

  const int b = blockIdx.x;
  const int tid = threadIdx.x;
  const int lane = tid & 63;
  const int wv = tid >> 6;      // wave 0..3 = M-tile
  const int quad = lane >> 4;   // 0..3
  const int l16 = lane & 15;

  const short* WT1g = wsw;                 // [48][288]
  const short* WT2g = wsw + WS_WT2OFF;     // [16][128]
  const float* F32 = (const float*)(wsw + WS_SHORTS);

  // ---------- P0: stage tiny fused f32 mats to LDS (overlaps P1) ----------
  c4up_lds[tid] = F32[F_C4UP + tid];
  c4up_lds[256 + tid] = F32[F_C4UP + 256 + tid];
  if (tid < 128) g4_lds[tid] = F32[F_G4 + tid];

  const int tok = wv * 16 + l16;
  const float* hrow = hg + ((size_t)b * NT + tok) * HD;
  const float* urow = ug2 + ((size_t)b * NT + tok) * UD;
  const float* zrow = zg + ((size_t)b * NT + tok) * ZD;

  // ---------- P1: GEMM1 A=[h|z] K=272(pad288), N=48 [q4|gate|cand]; GEMM2 A=u K=128, N=8 [k4|v4] ----------
  v4f acc1[3];
  for (int i = 0; i < 3; ++i) acc1[i] = (v4f){0.f, 0.f, 0.f, 0.f};
#pragma unroll
  for (int kc = 0; kc < 9; ++kc) {
    v8s a;
    if (kc < 8) {
      v4f x0 = *(const v4f*)(hrow + kc * 32 + quad * 8);
      v4f x1 = *(const v4f*)(hrow + kc * 32 + quad * 8 + 4);
      a = pack8(x0, x1);
    } else if (quad < 2) {  // k=256..271 -> z[0..15]
      v4f x0 = *(const v4f*)(zrow + quad * 8);
      v4f x1 = *(const v4f*)(zrow + quad * 8 + 4);
      a = pack8(x0, x1);
    } else {
      a = (v8s){0, 0, 0, 0, 0, 0, 0, 0};
    }
    const short* wrow = WT1g + kc * 32 + quad * 8;
#pragma unroll
    for (int nt = 0; nt < 3; ++nt) {
      v8s bb = ld8(wrow + (nt * 16 + l16) * 288);
      acc1[nt] = __builtin_amdgcn_mfma_f32_16x16x32_bf16(a, bb, acc1[nt], 0, 0, 0);
    }
  }
  v4f acc2 = (v4f){0.f, 0.f, 0.f, 0.f};
#pragma unroll
  for (int kc = 0; kc < 4; ++kc) {
    v4f x0 = *(const v4f*)(urow + kc * 32 + quad * 8);
    v4f x1 = *(const v4f*)(urow + kc * 32 + quad * 8 + 4);
    v8s a = pack8(x0, x1);
    v8s bb = ld8(WT2g + l16 * 128 + kc * 32 + quad * 8);
    acc2 = __builtin_amdgcn_mfma_f32_16x16x32_bf16(a, bb, acc2, 0, 0, 0);
  }

  // Epilogue (C/D: col=l16, row=quad*4+r, M-tile=wv) — all writes wave-local rows
  if (l16 < 4) {
#pragma unroll
    for (int r = 0; r < 4; ++r)
      q4s[(wv * 16 + quad * 4 + r) * 4 + l16] = acc1[0][r];
  }
#pragma unroll
  for (int r = 0; r < 4; ++r) {
    int row = wv * 16 + quad * 4 + r;
    g1out[row * 33 + l16] = acc1[1][r];
    g1out[row * 33 + 16 + l16] = acc1[2][r];
  }
  if (l16 < 8) {
#pragma unroll
    for (int r = 0; r < 4; ++r) {
      int row = wv * 16 + quad * 4 + r;
      kv8[row * 8 + wv * 4 + l16] = acc2[r];
    }
  }
  __syncthreads();  // barrier A: kv8/q4s consumed cross-wave in P2

  // ---------- P2: scores row n = (q4@M4)·k4^T, mask, softmax, attn out, cl4 = attn@v4 ----------
  const int n = tid >> 2, p = tid & 3;
  {
    v4f q4v = *(const v4f*)(q4s + n * 4);
    float M4v[16];
#pragma unroll
    for (int t = 0; t < 16; ++t) M4v[t] = F32[F_M4 + t];  // uniform -> s_load
    float qm[4];
#pragma unroll
    for (int s2 = 0; s2 < 4; ++s2)
      qm[s2] = q4v.x * M4v[s2] + q4v.y * M4v[4 + s2] + q4v.z * M4v[8 + s2] + q4v.w * M4v[12 + s2];

    float e[16];
    float mx = -INFINITY;
#pragma unroll
    for (int i = 0; i < 16; ++i) {
      int m = p * 16 + i;
      v4f k4 = *(const v4f*)(kv8 + m * 8 + p * 4);  // m>>4 == p
      float s = qm[0] * k4.x + qm[1] * k4.y + qm[2] * k4.z + qm[3] * k4.w;
      e[i] = (m == n) ? -INFINITY : s;
      mx = fmaxf(mx, e[i]);
    }
    mx = fmaxf(mx, __shfl_xor(mx, 1));
    mx = fmaxf(mx, __shfl_xor(mx, 2));
    float ssum = 0.f;
#pragma unroll
    for (int i = 0; i < 16; ++i) { float ee = __expf(e[i] - mx); e[i] = ee; ssum += ee; }
    ssum += __shfl_xor(ssum, 1);
    ssum += __shfl_xor(ssum, 2);
    float inv = 1.f / ssum;

    v4f cl = (v4f){0.f, 0.f, 0.f, 0.f};
#pragma unroll
    for (int i = 0; i < 16; ++i) {
      float av = e[i] * inv;   // diag: exp(-inf)=0 -> exact 0
      e[i] = av;
      int m = p * 16 + i;
      v4f v4 = *(const v4f*)(kv8 + m * 8 + p * 4 + 4);
      cl += av * v4;
    }
    size_t gb = ((size_t)b * NT + n) * NT + p * 16;
#pragma unroll
    for (int i = 0; i < 4; ++i)
      *(v4f*)(attn_o + gb + i * 4) = (v4f){e[4 * i], e[4 * i + 1], e[4 * i + 2], e[4 * i + 3]};
    // reduce cl over the 4 row-threads (same wave)
#pragma unroll
    for (int rnd = 1; rnd <= 2; rnd <<= 1) {
      cl.x += __shfl_xor(cl.x, rnd);
      cl.y += __shfl_xor(cl.y, rnd);
      cl.z += __shfl_xor(cl.z, rnd);
      cl.w += __shfl_xor(cl.w, rnd);
    }
    if (p == 0) *(v4f*)(cl4s + n * 4) = cl;  // wave-local consumer -> no barrier needed
  }

  // ---------- P3a: expand q,k,v = rank4 @ up * SCALE -> global f32 (wave-local LDS reads) ----------
  {
    float qup[4], kup[4], vup[4];
#pragma unroll
    for (int r = 0; r < 4; ++r) {
      qup[r] = qd_up[r * AD + lane];
      kup[r] = kd_up[r * AD + lane];
      vup[r] = vd_up[r * AD + lane];
    }
    for (int i = 0; i < 16; ++i) {
      int t = wv * 16 + i;
      v4f q4 = *(const v4f*)(q4s + t * 4);
      const float* kr = kv8 + t * 8 + wv * 4;  // t>>4 == wv
      v4f k4 = *(const v4f*)kr;
      v4f v4 = *(const v4f*)(kr + 4);
      float qv = LRSCALE * (q4.x * qup[0] + q4.y * qup[1] + q4.z * qup[2] + q4.w * qup[3]);
      float kv = LRSCALE * (k4.x * kup[0] + k4.y * kup[1] + k4.z * kup[2] + k4.w * kup[3]);
      float vv = LRSCALE * (v4.x * vup[0] + v4.y * vup[1] + v4.z * vup[2] + v4.w * vup[3]);
      size_t go = ((size_t)b * NT + t) * AD + lane;
      q_o[go] = qv; k_o[go] = kv; v_o[go] = vv;
    }
  }

  // ---------- P3b: c = cl4 @ C4UP -> global; g1out += cl4 @ G4 (all wave-local) ----------
  {
    v4f cl = *(const v4f*)(cl4s + n * 4);
    float* crow = c_o + ((size_t)b * NT + n) * UD;
#pragma unroll
    for (int k2 = 0; k2 < 8; ++k2) {
      int ch = p + 4 * k2;  // strided chunks: conflict-free LDS, coalesced store
      v4f acc = cl.x * *(const v4f*)(c4up_lds + 0 * 128 + ch * 4)
              + cl.y * *(const v4f*)(c4up_lds + 1 * 128 + ch * 4)
              + cl.z * *(const v4f*)(c4up_lds + 2 * 128 + ch * 4)
              + cl.w * *(const v4f*)(c4up_lds + 3 * 128 + ch * 4);
      *(v4f*)(crow + ch * 4) = acc;
    }
#pragma unroll
    for (int k2 = 0; k2 < 8; ++k2) {
      int o = p + 4 * k2;  // o in 0..31: gate cols 0..15, cand cols 16..31
      float add = cl.x * g4_lds[o] + cl.y * g4_lds[32 + o]
                + cl.z * g4_lds[64 + o] + cl.w * g4_lds[96 + o];
      g1out[n * 33 + o] += add;  // row n owned by this wave; unique (n,o) per thread
    }
  }
  __syncthreads();  // barrier B: g1out consumed cross-wave in P8

  // ---------- P8: gated update + layernorm ----------
  if (tid < NT) {
    const int t = tid;
    const float* zr = zg + ((size_t)b * NT + t) * ZD;
    float eta = 1.f / (1.f + __expf(-eta_logit[0]));
    float x[16];
    float mean = 0.f;
#pragma unroll
    for (int o = 0; o < 16; ++o) {
      float gpre = g1out[t * 33 + o] + ug_b[o];
      float cpre = g1out[t * 33 + 16 + o] + cand_b[o];
      float gate = 1.f / (1.f + __expf(-gpre));
      float prop = tanhf(cpre);
      float eg = eta * gate;
      float xv = (1.f - eg) * zr[o] + eg * prop;
      x[o] = xv;
      mean += xv;
    }
    mean *= (1.f / 16.f);
    float var = 0.f;
#pragma unroll
    for (int o = 0; o < 16; ++o) { float d0 = x[o] - mean; var += d0 * d0; }
    var *= (1.f / 16.f);
    float rs = rsqrtf(var + 1e-5f);
#pragma unroll
    for (int o = 0; o < 16; ++o)
      zn_o[((size_t)b * NT + t) * ZD + o] = (x[o] - mean) * rs;
  }
}

extern "C" void kernel_launch(void* const* d_in, const int* in_sizes, int n_in,
                              void* d_out, int out_size, void* d_ws, size_t ws_size,
                              hipStream_t stream) {
  const float* h = (const float*)d_in[0];
  const float* u = (const float*)d_in[1];
  const float* z = (const float*)d_in[2];
  const float* qd_down = (const float*)d_in[3];
  const float* qd_up = (const float*)d_in[4];
  const float* kd_down = (const float*)d_in[5];
  const float* kd_up = (const float*)d_in[6];
  const float* vd_down = (const float*)d_in[7];
  const float* vd_up = (const float*)d_in[8];
  const float* od_down = (const float*)d_in[9];
  const float* od_up = (const float*)d_in[10];
  const float* ug_w = (const float*)d_in[11];
  const float* ug_b = (const float*)d_in[12];
  const float* cand_w = (const float*)d_in[13];
  const float* cand_b = (const float*)d_in[14];
  const float* eta_logit = (const float*)d_in[15];
  float* out = (float*)d_out;
  short* ws = (short*)d_ws;

  // Stage 1: bf16 weight transposes + rank-4 fused f32 mats (M4, C4UP, G4).
  prep_weights<<<8, 256, 0, stream>>>(
      qd_down, qd_up, kd_down, kd_up, vd_down, vd_up,
      od_down, od_up, ug_w, cand_w, ws);

  // Stage 2: fused main kernel, one block per batch.
  memetic_fused<<<NBATCH, 256, 0, stream>>>(
      h, u, z, qd_up, kd_up, vd_up, ug_b, cand_b, eta_logit, ws,
      out + OFF_C, out + OFF_ZN, out + OFF_ATTN,
      out + OFF_Q, out + OFF_K, out + OFF_V);
}